// Round 14
// baseline (163.897 us; speedup 1.0000x reference)
//
#include <hip/hip_runtime.h>
#include <hip/hip_bf16.h>
#include <math.h>

// ---------------------------------------------------------------------------
// Bundle recommendation forward (BGCN-style).
// r13 changes vs r12:
//  - layers: dual edge-streams per row (two independent accumulator sets,
//    interleaved loads) -> ~2x outstanding gathers per wave. Layers proved
//    latency-bound (r12: FETCH -12MB, dur unchanged; VALU/HBM/Occ all low).
//  - keeps r12's XCD swizzle (free FETCH reduction) and everything else.
// ---------------------------------------------------------------------------

typedef unsigned short ushortT;
#define CHUNK 8192

__device__ __forceinline__ float wSum(float v) {
#pragma unroll
    for (int o = 32; o >= 1; o >>= 1) v += __shfl_xor(v, o, 64);
    return v;
}
__device__ __forceinline__ float wMax(float v) {
#pragma unroll
    for (int o = 32; o >= 1; o >>= 1) v = fmaxf(v, __shfl_xor(v, o, 64));
    return v;
}
__device__ __forceinline__ float bf2f(ushortT u) {
    return __uint_as_float(((unsigned int)u) << 16);
}
__device__ __forceinline__ ushortT f2bf(float f) {  // round-nearest-even
    unsigned int x = __float_as_uint(f);
    return (ushortT)((x + 0x7fffu + ((x >> 16) & 1u)) >> 16);
}
__device__ __forceinline__ void up2(unsigned int u, float& lo, float& hi) {
    lo = __uint_as_float(u << 16);
    hi = __uint_as_float(u & 0xffff0000u);
}
__device__ __forceinline__ unsigned int pk2(float lo, float hi) {
    return ((unsigned int)f2bf(hi) << 16) | f2bf(lo);
}

__global__ void zero_ints(int* __restrict__ p, int n) {
    int i = blockIdx.x * blockDim.x + threadIdx.x;
    if (i < n) p[i] = 0;
}

// fallback: atomic global histogram of item-side degrees
__global__ void hist_at(const int* __restrict__ colsA, int halfA, int nAA, int* __restrict__ cntA,
                        const int* __restrict__ colsB, int halfB, int nAB, int* __restrict__ cntB) {
    int i = blockIdx.x * blockDim.x + threadIdx.x;
    if (i < halfA) atomicAdd(&cntA[colsA[i] - nAA], 1);
    else if (i < halfA + halfB) {
        int j = i - halfA;
        atomicAdd(&cntB[colsB[j] - nAB], 1);
    }
}

// fused: per-chunk LDS coarse histogram (bucket-major out) + bf16 f0 build
__global__ void prep_f(
    const int* __restrict__ colsA, int halfA, int nblkA, int cpbA,
    int* __restrict__ histTA,
    const int* __restrict__ colsB, int halfB, int nblkB, int cpbB,
    int* __restrict__ histTB,
    int nA0,
    const float* __restrict__ uf, const float* __restrict__ itf,
    const float* __restrict__ buf,
    ushortT* __restrict__ f0A, int nTotA,
    ushortT* __restrict__ f0B, int nTotB) {
    __shared__ int h[256];
    int blk = blockIdx.x, t = threadIdx.x;
    int edgeBlks = nblkA + nblkB;
    if (blk < edgeBlks) {
        const int* cols; int half, nblk, cpb, k; int* histT;
        if (blk < nblkA) { cols = colsA; half = halfA; nblk = nblkA; cpb = cpbA; histT = histTA; k = blk; }
        else             { cols = colsB; half = halfB; nblk = nblkB; cpb = cpbB; histT = histTB; k = blk - nblkA; }
        h[t] = 0;
        __syncthreads();
        int s = k * CHUNK, e = min(s + CHUNK, half);
        for (int i = s + t; i < e; i += 256) atomicAdd(&h[(cols[i] - nA0) / cpb], 1);
        __syncthreads();
        histT[t * nblk + k] = h[t];  // bucket-major
    } else {
        int idx = (blk - edgeBlks) * 256 + t;
        int totA = nTotA * 64;
        if (idx < totA) {
            int r = idx >> 6;
            f0A[idx] = f2bf((r < nA0) ? uf[idx] : itf[idx - nA0 * 64]);
        } else if (idx < totA + nTotB * 64) {
            int j = idx - totA;
            int r = j >> 6;
            f0B[j] = f2bf((r < nA0) ? uf[j] : buf[j - nA0 * 64]);
        }
    }
}

// --- 2-array hierarchical scan ---
__global__ void scan1h(const int* c0, int n0, int nb0, int* p0,
                       const int* c1, int n1, int nb1, int* p1) {
    int blk = blockIdx.x, t = threadIdx.x;
    const int* cnt; int n; int* part; int cb;
    if (blk < nb0) { cnt = c0; n = n0; part = p0; cb = blk; }
    else           { cnt = c1; n = n1; part = p1; cb = blk - nb0; }
    int i = cb * 256 + t;
    int v = (i < n) ? cnt[i] : 0;
#pragma unroll
    for (int o = 32; o >= 1; o >>= 1) v += __shfl_xor(v, o, 64);
    __shared__ int sm[4];
    if ((t & 63) == 0) sm[t >> 6] = v;
    __syncthreads();
    if (t == 0) part[cb] = sm[0] + sm[1] + sm[2] + sm[3];
}

// 2-array scan pass 2: per-block base reduction (strided, any cb) + local
// exclusive scan. Optional cur copy + tail write.
__global__ void scan3h(const int* c0, int n0, int nb0, const int* p0, int* o0, int* u0, int t0,
                       const int* c1, int n1, int nb1, const int* p1, int* o1, int* u1, int t1) {
    __shared__ int sm[256];
    int blk = blockIdx.x, t = threadIdx.x;
    const int *cnt, *part; int *ofs, *cur; int n, cb, tail;
    if (blk < nb0) { cnt = c0; n = n0; part = p0; ofs = o0; cur = u0; cb = blk; tail = t0; }
    else           { cnt = c1; n = n1; part = p1; ofs = o1; cur = u1; cb = blk - nb0; tail = t1; }
    int acc = 0;
    for (int j = t; j < cb; j += 256) acc += part[j];
    sm[t] = acc;
    __syncthreads();
    for (int o = 128; o >= 1; o >>= 1) {
        if (t < o) sm[t] += sm[t + o];
        __syncthreads();
    }
    int base = sm[0];
    __syncthreads();
    int i = cb * 256 + t;
    int v = (i < n) ? cnt[i] : 0;
    sm[t] = v;
    __syncthreads();
    for (int o = 1; o < 256; o <<= 1) {
        int x = (t >= o) ? sm[t - o] : 0;
        __syncthreads();
        sm[t] += x;
        __syncthreads();
    }
    int excl = sm[t] - v + base;
    if (i < n) {
        ofs[i] = excl;
        if (cur) cur[i] = excl;
        if (tail && i == n - 1) ofs[n] = excl + v;
    }
}

// pass 1b: scatter packed (col<<16|user) into bucket-contiguous regions
__global__ void p1scat(const int* __restrict__ rowsA, const int* __restrict__ colsA,
                       int halfA, int nblkA, int cpbA, int nAA,
                       const int* __restrict__ hsA, unsigned int* __restrict__ pairA,
                       const int* __restrict__ rowsB, const int* __restrict__ colsB,
                       int halfB, int nblkB, int cpbB, int nAB,
                       const int* __restrict__ hsB, unsigned int* __restrict__ pairB) {
    __shared__ int cur[256];
    int blk = blockIdx.x, t = threadIdx.x;
    const int *rows, *cols, *hs; int half, nblk, cpb, nA0, k; unsigned int* pair;
    if (blk < nblkA) { rows = rowsA; cols = colsA; hs = hsA; pair = pairA;
                       half = halfA; nblk = nblkA; cpb = cpbA; nA0 = nAA; k = blk; }
    else             { rows = rowsB; cols = colsB; hs = hsB; pair = pairB;
                       half = halfB; nblk = nblkB; cpb = cpbB; nA0 = nAB; k = blk - nblkA; }
    cur[t] = hs[t * nblk + k];
    __syncthreads();
    int s = k * CHUNK, e = min(s + CHUNK, half);
    for (int i = s + t; i < e; i += 256) {
        int c = cols[i] - nA0;
        int pos = atomicAdd(&cur[c / cpb], 1);
        pair[pos] = ((unsigned int)c << 16) | (unsigned int)rows[i];
    }
}

// pass 2: one block per coarse bucket. Computes per-column offsets LOCALLY
// (LDS histogram + scan over <=256 columns), writes ofs[] AND exact-CSR tu[].
__global__ void p2scat_ofs(
    const unsigned int* __restrict__ pairA, const int* __restrict__ hsA,
    int nblkA, int halfA, int cpbA, int nColsA,
    int* __restrict__ ofsA, int* __restrict__ tuA,
    const unsigned int* __restrict__ pairB, const int* __restrict__ hsB,
    int nblkB, int halfB, int cpbB, int nColsB,
    int* __restrict__ ofsB, int* __restrict__ tuB) {
    __shared__ int lcnt[256];
    __shared__ int lofs[256];
    int blk = blockIdx.x, t = threadIdx.x;
    const unsigned int* pair; const int* hs; int nblk, half, cpb, nCols, b; int *ofs, *tu;
    if (blk < 256) { pair = pairA; hs = hsA; nblk = nblkA; half = halfA; cpb = cpbA;
                     nCols = nColsA; ofs = ofsA; tu = tuA; b = blk; }
    else           { pair = pairB; hs = hsB; nblk = nblkB; half = halfB; cpb = cpbB;
                     nCols = nColsB; ofs = ofsB; tu = tuB; b = blk - 256; }
    int c0 = b * cpb;
    if (c0 >= nCols) return;
    int c1 = min(c0 + cpb, nCols);
    int w = c1 - c0;
    int s = hs[b * nblk];
    int e = (b == 255) ? half : hs[(b + 1) * nblk];
    lcnt[t] = 0;
    __syncthreads();
    for (int i = s + t; i < e; i += 256)
        atomicAdd(&lcnt[(int)(pair[i] >> 16) - c0], 1);
    __syncthreads();
    int v = lcnt[t];
    lofs[t] = v;
    __syncthreads();
    for (int o = 1; o < 256; o <<= 1) {
        int x = (t >= o) ? lofs[t - o] : 0;
        __syncthreads();
        lofs[t] += x;
        __syncthreads();
    }
    int excl = lofs[t] - v + s;   // global CSR offset of column c0+t
    if (t < w) ofs[c0 + t] = excl;
    if (t == 0 && c1 == nCols) ofs[nCols] = e;
    __syncthreads();
    lofs[t] = excl;               // cursors
    __syncthreads();
    for (int i = s + t; i < e; i += 256) {
        unsigned int pr = pair[i];
        int pos = atomicAdd(&lofs[(int)(pr >> 16) - c0], 1);
        tu[pos] = (int)(pr & 0xffffu);
    }
}

// fallback scatter (generic shapes)
__global__ void scatter2(const int* __restrict__ rowsA, const int* __restrict__ colsA,
                         int nAA, int halfA, int* __restrict__ curA, int* __restrict__ tuA,
                         const int* __restrict__ rowsB, const int* __restrict__ colsB,
                         int nAB, int halfB, int* __restrict__ curB, int* __restrict__ tuB) {
    int i = blockIdx.x * blockDim.x + threadIdx.x;
    if (i < halfA) {
        int c = colsA[i] - nAA;
        int p = atomicAdd(&curA[c], 1);
        tuA[p] = rowsA[i];
    } else if (i < halfA + halfB) {
        int j = i - halfA;
        int c = colsB[j] - nAB;
        int p = atomicAdd(&curB[c], 1);
        tuB[p] = rowsB[j];
    }
}

// octet layer body: octet handles one row; lane p owns dims [8p..8p+7].
// Dual edge-streams: two independent accumulator sets, interleaved loads.
// LAST=0: write f1 (bf16) + nrm[row]=inv_nrm.
// LAST=1: accOut = bf16(orig_f32 + f1*nrm1 + f2*inv_nrm2).
template <int DEG, int LAST>
__device__ __forceinline__ void layer8_body(
    const int* __restrict__ cols, const float* __restrict__ vals,
    const int* __restrict__ ofs, const int* __restrict__ tuser,
    const ushortT* __restrict__ f, ushortT* __restrict__ fnext,
    float* __restrict__ nrm,
    const float* __restrict__ origU, const float* __restrict__ origO,
    ushortT* __restrict__ accOut,
    int row, int p, int nA, int nTot, int deg, float invu, float inv_s) {
    if (row >= nTot) return;  // whole octet inactive together
    float a[8] = {0.f, 0.f, 0.f, 0.f, 0.f, 0.f, 0.f, 0.f};
    float b8[8] = {0.f, 0.f, 0.f, 0.f, 0.f, 0.f, 0.f, 0.f};
    if (row < nA) {
        const int* cp = cols + (long)row * deg;
        const float* vp = vals + (long)row * deg;
        if constexpr (DEG > 0) {
            constexpr int H = DEG / 2;
#pragma unroll
            for (int e = 0; e < H; ++e) {
                int c0 = cp[e];
                int c1 = cp[e + H];
                float v0 = vp[e];
                float v1 = vp[e + H];
                uint4 r0 = *(const uint4*)(f + ((long)c0 << 6) + (p << 3));
                uint4 r1 = *(const uint4*)(f + ((long)c1 << 6) + (p << 3));
                float x0, x1;
                up2(r0.x, x0, x1); a[0] = fmaf(v0, x0, a[0]);  a[1] = fmaf(v0, x1, a[1]);
                up2(r1.x, x0, x1); b8[0] = fmaf(v1, x0, b8[0]); b8[1] = fmaf(v1, x1, b8[1]);
                up2(r0.y, x0, x1); a[2] = fmaf(v0, x0, a[2]);  a[3] = fmaf(v0, x1, a[3]);
                up2(r1.y, x0, x1); b8[2] = fmaf(v1, x0, b8[2]); b8[3] = fmaf(v1, x1, b8[3]);
                up2(r0.z, x0, x1); a[4] = fmaf(v0, x0, a[4]);  a[5] = fmaf(v0, x1, a[5]);
                up2(r1.z, x0, x1); b8[4] = fmaf(v1, x0, b8[4]); b8[5] = fmaf(v1, x1, b8[5]);
                up2(r0.w, x0, x1); a[6] = fmaf(v0, x0, a[6]);  a[7] = fmaf(v0, x1, a[7]);
                up2(r1.w, x0, x1); b8[6] = fmaf(v1, x0, b8[6]); b8[7] = fmaf(v1, x1, b8[7]);
            }
            if constexpr (DEG & 1) {
                int c = cp[DEG - 1];
                float vv = vp[DEG - 1];
                uint4 rv = *(const uint4*)(f + ((long)c << 6) + (p << 3));
                float x0, x1;
                up2(rv.x, x0, x1); a[0] = fmaf(vv, x0, a[0]); a[1] = fmaf(vv, x1, a[1]);
                up2(rv.y, x0, x1); a[2] = fmaf(vv, x0, a[2]); a[3] = fmaf(vv, x1, a[3]);
                up2(rv.z, x0, x1); a[4] = fmaf(vv, x0, a[4]); a[5] = fmaf(vv, x1, a[5]);
                up2(rv.w, x0, x1); a[6] = fmaf(vv, x0, a[6]); a[7] = fmaf(vv, x1, a[7]);
            }
        } else {
#pragma unroll 4
            for (int e = 0; e < deg; ++e) {
                int c = cp[e];
                float vv = vp[e];
                uint4 rv = *(const uint4*)(f + ((long)c << 6) + (p << 3));
                float x0, x1;
                up2(rv.x, x0, x1); a[0] = fmaf(vv, x0, a[0]); a[1] = fmaf(vv, x1, a[1]);
                up2(rv.y, x0, x1); a[2] = fmaf(vv, x0, a[2]); a[3] = fmaf(vv, x1, a[3]);
                up2(rv.z, x0, x1); a[4] = fmaf(vv, x0, a[4]); a[5] = fmaf(vv, x1, a[5]);
                up2(rv.w, x0, x1); a[6] = fmaf(vv, x0, a[6]); a[7] = fmaf(vv, x1, a[7]);
            }
        }
#pragma unroll
        for (int d = 0; d < 8; ++d) a[d] += b8[d];
    } else {
        int r2 = row - nA;
        int s = ofs[r2], e2 = ofs[r2 + 1];
        int cnt = e2 - s;
        int h = cnt >> 1;
        int mid = s + h;
#pragma unroll 4
        for (int j = 0; j < h; ++j) {
            int u0 = tuser[s + j];
            int u1 = tuser[mid + j];
            uint4 r0 = *(const uint4*)(f + ((long)u0 << 6) + (p << 3));
            uint4 r1 = *(const uint4*)(f + ((long)u1 << 6) + (p << 3));
            float x0, x1;
            up2(r0.x, x0, x1); a[0] += x0;  a[1] += x1;
            up2(r1.x, x0, x1); b8[0] += x0; b8[1] += x1;
            up2(r0.y, x0, x1); a[2] += x0;  a[3] += x1;
            up2(r1.y, x0, x1); b8[2] += x0; b8[3] += x1;
            up2(r0.z, x0, x1); a[4] += x0;  a[5] += x1;
            up2(r1.z, x0, x1); b8[4] += x0; b8[5] += x1;
            up2(r0.w, x0, x1); a[6] += x0;  a[7] += x1;
            up2(r1.w, x0, x1); b8[6] += x0; b8[7] += x1;
        }
        if (cnt & 1) {
            int uu = tuser[e2 - 1];
            uint4 rv = *(const uint4*)(f + ((long)uu << 6) + (p << 3));
            float x0, x1;
            up2(rv.x, x0, x1); a[0] += x0; a[1] += x1;
            up2(rv.y, x0, x1); a[2] += x0; a[3] += x1;
            up2(rv.z, x0, x1); a[4] += x0; a[5] += x1;
            up2(rv.w, x0, x1); a[6] += x0; a[7] += x1;
        }
        float invi = 1.f / (sqrtf((float)cnt) + 1e-8f);
        float sc = invi * invu;
#pragma unroll
        for (int d = 0; d < 8; ++d) a[d] = (a[d] + b8[d]) * sc;
    }
    float ss = 0.f;
#pragma unroll
    for (int d = 0; d < 8; ++d) {
        a[d] *= inv_s;
        ss = fmaf(a[d], a[d], ss);
    }
    ss += __shfl_xor(ss, 1, 64);
    ss += __shfl_xor(ss, 2, 64);
    ss += __shfl_xor(ss, 4, 64);
    float inv_nrm = 1.f / fmaxf(sqrtf(ss), 1e-12f);
    long base = ((long)row << 6) + (p << 3);
    if constexpr (!LAST) {
        if (p == 0) nrm[row] = inv_nrm;
        uint4 fb;
        fb.x = pk2(a[0], a[1]);
        fb.y = pk2(a[2], a[3]);
        fb.z = pk2(a[4], a[5]);
        fb.w = pk2(a[6], a[7]);
        *(uint4*)(fnext + base) = fb;
    } else {
        const float* op = (row < nA) ? (origU + base)
                                     : (origO + (((long)(row - nA)) << 6) + (p << 3));
        float4 c0 = *(const float4*)op;
        float4 c1 = *(const float4*)(op + 4);
        float n1 = nrm[row];
        uint4 f1v = *(const uint4*)(f + base);   // own row of layer-1 output
        float x0, x1, x2, x3, x4, x5, x6, x7;
        up2(f1v.x, x0, x1);
        up2(f1v.y, x2, x3);
        up2(f1v.z, x4, x5);
        up2(f1v.w, x6, x7);
        uint4 ob;
        ob.x = pk2(c0.x + x0 * n1 + a[0] * inv_nrm, c0.y + x1 * n1 + a[1] * inv_nrm);
        ob.y = pk2(c0.z + x2 * n1 + a[2] * inv_nrm, c0.w + x3 * n1 + a[3] * inv_nrm);
        ob.z = pk2(c1.x + x4 * n1 + a[4] * inv_nrm, c1.y + x5 * n1 + a[5] * inv_nrm);
        ob.w = pk2(c1.z + x6 * n1 + a[6] * inv_nrm, c1.w + x7 * n1 + a[7] * inv_nrm);
        *(uint4*)(accOut + base) = ob;
    }
}

template <int DA, int DB, int LAST>
__global__ void __launch_bounds__(256) layer8_fused(
    const int* colsA, const float* valsA, const int* ofsA, const int* tuA,
    const ushortT* fA, ushortT* fnA, float* nrmA,
    const float* origUA, const float* origOA, ushortT* accOutA,
    int nAA, int nTotA, int degA, float invuA,
    const int* colsB, const float* valsB, const int* ofsB, const int* tuB,
    const ushortT* fB, ushortT* fnB, float* nrmB,
    const float* origUB, const float* origOB, ushortT* accOutB,
    int nAB, int nTotB, int degB, float invuB,
    float inv_s) {
    // bijective chunked XCD swizzle (T1/m204): each XCD gets a contiguous
    // block span -> type-pure gather working set per XCD L2.
    int nwg = gridDim.x;
    int bid = blockIdx.x;
    int q = nwg >> 3, r = nwg & 7;
    int xcd = bid & 7, ord = bid >> 3;
    int wg = ((xcd < r) ? xcd * (q + 1) : r * (q + 1) + (xcd - r) * q) + ord;
    int gw = (wg * 256 + (int)threadIdx.x) >> 6;
    int lane = threadIdx.x & 63;
    int oct = lane >> 3, p = lane & 7;
    int wA = (nTotA + 7) >> 3;
    int wB = (nTotB + 7) >> 3;
    if (gw < wA) {
        layer8_body<DA, LAST>(colsA, valsA, ofsA, tuA, fA, fnA, nrmA, origUA, origOA, accOutA,
                              gw * 8 + oct, p, nAA, nTotA, degA, invuA, inv_s);
    } else if (gw < wA + wB) {
        layer8_body<DB, LAST>(colsB, valsB, ofsB, tuB, fB, fnB, nrmB, origUB, origOB, accOutB,
                              (gw - wA) * 8 + oct, p, nAB, nTotB, degB, invuB, inv_s);
    }
}

// one wave per batch row; K bundles per wave. MM = compile-time bundle size
// (must be divisible by 8).
template <int MM>
__global__ void __launch_bounds__(256) score_kernel_t(
    const ushortT* __restrict__ accIL, const ushortT* __restrict__ accBL,
    const int* __restrict__ bitem, const unsigned char* __restrict__ mask8,
    const int* __restrict__ users, const int* __restrict__ bundles,
    const float* __restrict__ fw1, const float* __restrict__ fb1,
    const float* __restrict__ fw2, const float* __restrict__ fb2,
    float* __restrict__ out, int U, int K, int B) {
    int b = (blockIdx.x * blockDim.x + threadIdx.x) >> 6;
    int lane = threadIdx.x & 63;
    if (b >= B) return;
    // mask layout self-detection (lengths >= 10 so element 1 is True):
    // u8-bool -> byte 1 == 1 ; int32 -> byte 1 == 0 (high byte of value 1)
    bool mu8 = (mask8[1] != 0);
    const int* m32 = (const int*)mask8;

    int u = users[b];
    const ushortT* qrow = accIL + ((long)u << 6);
    float q = bf2f(qrow[lane]);
    float blu = bf2f(accBL[((long)u << 6) + lane]);

    // q fragment for 8-lane dots: this lane's 8 dims [8*pos .. 8*pos+7]
    int pos = lane & 7;
    uint4 qv = *(const uint4*)(qrow + (pos << 3));
    float q8[8];
    up2(qv.x, q8[0], q8[1]);
    up2(qv.y, q8[2], q8[3]);
    up2(qv.z, q8[4], q8[5]);
    up2(qv.w, q8[6], q8[7]);

    // gate MLP (user-dependent only), 4 independent accumulator chains
    float h0 = fb1[lane], h1 = 0.f, h2 = 0.f, h3 = 0.f;
#pragma unroll
    for (int i = 0; i < 64; i += 4) {
        h0 = fmaf(__shfl(q, i, 64),     fw1[i * 64 + lane],       h0);
        h1 = fmaf(__shfl(q, i + 1, 64), fw1[(i + 1) * 64 + lane], h1);
        h2 = fmaf(__shfl(q, i + 2, 64), fw1[(i + 2) * 64 + lane], h2);
        h3 = fmaf(__shfl(q, i + 3, 64), fw1[(i + 3) * 64 + lane], h3);
    }
#pragma unroll
    for (int i = 0; i < 64; i += 4) {
        h0 = fmaf(__shfl(blu, i, 64),     fw1[(64 + i) * 64 + lane],     h0);
        h1 = fmaf(__shfl(blu, i + 1, 64), fw1[(64 + i + 1) * 64 + lane], h1);
        h2 = fmaf(__shfl(blu, i + 2, 64), fw1[(64 + i + 2) * 64 + lane], h2);
        h3 = fmaf(__shfl(blu, i + 3, 64), fw1[(64 + i + 3) * 64 + lane], h3);
    }
    float h = fmaxf((h0 + h1) + (h2 + h3), 0.f);
    float gd = wSum(h * fw2[lane]) + fb2[0];
    float g = 1.f / (1.f + __expf(-gd));

    for (int k = 0; k < K; ++k) {
        int bd = bundles[b * K + k];
        float blb = bf2f(accBL[((long)(U + bd)) * 64 + lane]);
        long ib = (long)bd * MM;
        int idl = (lane < MM) ? bitem[ib + lane] : 0;
        bool mv = (lane < MM) ? (mu8 ? (mask8[ib + lane] != 0) : (m32[ib + lane] != 0))
                              : false;
        unsigned long long vmask = __ballot(mv);

        float el = -1e30f, lr = 0.f;  // lane m ends up holding logit m
#pragma unroll
        for (int i = 0; i < MM / 8; ++i) {
            // octet (lane>>3) computes item 8*i + (lane>>3)
            int id = __shfl(idl, 8 * i + (lane >> 3), 64);
            uint4 rv = *(const uint4*)(accIL + (((long)(U + id)) << 6) + (pos << 3));
            float a0, a1, s;
            up2(rv.x, a0, a1);
            s = fmaf(q8[0], a0, q8[1] * a1);
            up2(rv.y, a0, a1);
            s = fmaf(q8[2], a0, fmaf(q8[3], a1, s));
            up2(rv.z, a0, a1);
            s = fmaf(q8[4], a0, fmaf(q8[5], a1, s));
            up2(rv.w, a0, a1);
            s = fmaf(q8[6], a0, fmaf(q8[7], a1, s));
            // butterfly within the 8-lane group: all 8 lanes get the dot
            s += __shfl_xor(s, 1, 64);
            s += __shfl_xor(s, 2, 64);
            s += __shfl_xor(s, 4, 64);
            // assemble to lane m = 8*i + oct: read from octet (lane&7)
            float v = __shfl(s, (lane & 7) << 3, 64);
            if ((lane >> 3) == i) {
                lr = v;
                el = ((vmask >> lane) & 1ull) ? v : -1e9f;
            }
        }
        float bl = wSum(blu * blb);
        float maxl = wMax(el);
        float pe = __expf(el - maxl);   // lanes >= MM: exp(-inf) -> 0
        float sum = wSum(pe);
        float il = wSum(pe * lr) / sum;
        if (lane == 0) out[b * K + k] = g * il + (1.f - g) * bl;
    }
}

// generic-M fallback (runtime M)
__global__ void __launch_bounds__(256) score_kernel_gen(
    const ushortT* __restrict__ accIL, const ushortT* __restrict__ accBL,
    const int* __restrict__ bitem, const unsigned char* __restrict__ mask8,
    const int* __restrict__ users, const int* __restrict__ bundles,
    const float* __restrict__ fw1, const float* __restrict__ fb1,
    const float* __restrict__ fw2, const float* __restrict__ fb2,
    float* __restrict__ out, int U, int M, int K, int B) {
    int b = (blockIdx.x * blockDim.x + threadIdx.x) >> 6;
    int lane = threadIdx.x & 63;
    if (b >= B) return;
    bool mu8 = (mask8[1] != 0);
    const int* m32 = (const int*)mask8;
    int u = users[b];
    float q = bf2f(accIL[((long)u << 6) + lane]);
    float blu = bf2f(accBL[((long)u << 6) + lane]);
    float h = fb1[lane];
#pragma unroll 8
    for (int i = 0; i < 64; ++i) h = fmaf(__shfl(q, i, 64), fw1[i * 64 + lane], h);
#pragma unroll 8
    for (int i = 0; i < 64; ++i) h = fmaf(__shfl(blu, i, 64), fw1[(64 + i) * 64 + lane], h);
    h = fmaxf(h, 0.f);
    float gd = wSum(h * fw2[lane]) + fb2[0];
    float g = 1.f / (1.f + __expf(-gd));
    for (int k = 0; k < K; ++k) {
        int bd = bundles[b * K + k];
        float blb = bf2f(accBL[((long)(U + bd)) * 64 + lane]);
        float bl = wSum(blu * blb);
        long ib = (long)bd * M;
        int idl = (lane < M) ? bitem[ib + lane] : 0;
        bool mv = (lane < M) ? (mu8 ? (mask8[ib + lane] != 0) : (m32[ib + lane] != 0))
                             : false;
        unsigned long long vmask = __ballot(mv);
        float el = -1e30f, lr = 0.f;
#pragma unroll 8
        for (int m = 0; m < M; ++m) {
            int id = __shfl(idl, m, 64);
            float it = bf2f(accIL[((long)(U + id)) * 64 + lane]);
            float l = wSum(q * it);
            float lm = ((vmask >> m) & 1ull) ? l : -1e9f;
            if (lane == m) { el = lm; lr = l; }
        }
        float maxl = wMax(el);
        float pe = __expf(el - maxl);
        float sum = wSum(pe);
        float il = wSum(pe * lr) / sum;
        if (lane == 0) out[b * K + k] = g * il + (1.f - g) * bl;
    }
}

extern "C" void kernel_launch(void* const* d_in, const int* in_sizes, int n_in,
                              void* d_out, int out_size, void* d_ws, size_t ws_size,
                              hipStream_t stream) {
    const float* users_feature   = (const float*)d_in[0];
    const float* items_feature   = (const float*)d_in[1];
    const float* bundles_feature = (const float*)d_in[2];
    const float* fw1 = (const float*)d_in[3];
    const float* fb1 = (const float*)d_in[4];
    const float* fw2 = (const float*)d_in[5];
    const float* fb2 = (const float*)d_in[6];
    const int*   il_rows = (const int*)d_in[7];
    const int*   il_cols = (const int*)d_in[8];
    const float* il_vals = (const float*)d_in[9];
    const int*   bl_rows = (const int*)d_in[10];
    const int*   bl_cols = (const int*)d_in[11];
    const float* bl_vals = (const float*)d_in[12];
    const int*   bitem   = (const int*)d_in[13];
    const unsigned char* bmask = (const unsigned char*)d_in[14];
    const int*   users   = (const int*)d_in[15];
    const int*   bundles = (const int*)d_in[16];

    const int D = 64;
    int U  = in_sizes[0] / D;
    int I  = in_sizes[1] / D;
    int NB = in_sizes[2] / D;
    int nnzIL = in_sizes[7];
    int nnzBL = in_sizes[10];
    int degUI = (nnzIL / 2) / U;
    int degUB = (nnzBL / 2) / U;
    int M = in_sizes[13] / NB;
    int BATCH = in_sizes[15];
    int K = in_sizes[16] / BATCH;
    int nIL = U + I;
    int nBL = U + NB;
    int halfIL = U * degUI;
    int halfBL = U * degUB;

    char* wsB = (char*)d_ws;
    size_t off = 0;
    auto alc = [&](size_t bytes) -> void* {
        void* p = wsB + off;
        off = (off + bytes + 255) & ~(size_t)255;
        return p;
    };
    ushortT* accILbf = (ushortT*)alc((size_t)nIL * 64 * 2);
    ushortT* accBLbf = (ushortT*)alc((size_t)nBL * 64 * 2);
    ushortT* f0A = (ushortT*)alc((size_t)nIL * 64 * 2);
    ushortT* f1A = (ushortT*)alc((size_t)nIL * 64 * 2);
    ushortT* f0B = (ushortT*)alc((size_t)nBL * 64 * 2);
    ushortT* f1B = (ushortT*)alc((size_t)nBL * 64 * 2);
    float* nrmA = (float*)alc((size_t)nIL * 4);
    float* nrmB = (float*)alc((size_t)nBL * 4);
    int* ofsIL = (int*)alc((size_t)(I + 1) * 4);
    int* tuIL  = (int*)alc((size_t)halfIL * 4);
    int* ofsBL = (int*)alc((size_t)(NB + 1) * 4);
    int* tuBL  = (int*)alc((size_t)halfBL * 4);
    int* cnt   = (int*)alc((size_t)(I + NB) * 4);   // fallback only
    int* cur   = (int*)alc((size_t)(I + NB) * 4);   // fallback only
    int* cntIL = cnt,  *cntBL = cnt + I;
    int* curIL = cur,  *curBL = cur + I;

    // sort-path scratch
    int nblkA = (halfIL + CHUNK - 1) / CHUNK;
    int nblkB = (halfBL + CHUNK - 1) / CHUNK;
    int cpbA = (I + 255) / 256;
    int cpbB = (NB + 255) / 256;
    int LA = 256 * nblkA, LB = 256 * nblkB;
    unsigned int* pairIL = (unsigned int*)alc((size_t)halfIL * 4);
    unsigned int* pairBL = (unsigned int*)alc((size_t)halfBL * 4);
    int* histTA = (int*)alc((size_t)LA * 4);
    int* histSA = (int*)alc((size_t)(LA + 1) * 4);
    int* histTB = (int*)alc((size_t)LB * 4);
    int* histSB = (int*)alc((size_t)(LB + 1) * 4);
    int* part0  = (int*)alc(256 * 4);
    int* part1  = (int*)alc(256 * 4);

    float suA = sqrtf((float)degUI) + 1e-8f;
    float suB = sqrtf((float)degUB) + 1e-8f;

    // 1. edge pass (coarse histogram) || bf16 f0 build
    int elemsTot = (nIL + nBL) * 64;
    int initBlks = (elemsTot + 255) / 256;
    prep_f<<<nblkA + nblkB + initBlks, 256, 0, stream>>>(
        il_cols, halfIL, nblkA, cpbA, histTA,
        bl_cols, halfBL, nblkB, cpbB, histTB,
        U, users_feature, items_feature, bundles_feature,
        f0A, nIL, f0B, nBL);

    bool fast = (I < 65536) && (NB < 65536) && (U < 65536) &&
                (cpbA <= 256) && (cpbB <= 256) &&
                (nblkA >= 1) && (nblkB >= 1) && (nblkA <= 256) && (nblkB <= 256);
    if (fast) {
        // 2-3. scan of bucket-major hist matrices -> per-(bucket,chunk) bases
        scan1h<<<nblkA + nblkB, 256, 0, stream>>>(histTA, LA, nblkA, part0,
                                                  histTB, LB, nblkB, part1);
        scan3h<<<nblkA + nblkB, 256, 0, stream>>>(
            histTA, LA, nblkA, part0, histSA, nullptr, 0,
            histTB, LB, nblkB, part1, histSB, nullptr, 0);
        // 4. bucket-binning scatter (packed col<<16|user)
        p1scat<<<nblkA + nblkB, 256, 0, stream>>>(
            il_rows, il_cols, halfIL, nblkA, cpbA, U, histSA, pairIL,
            bl_rows, bl_cols, halfBL, nblkB, cpbB, U, histSB, pairBL);
        // 5. per-bucket exact CSR build: local column offsets + tu scatter
        p2scat_ofs<<<512, 256, 0, stream>>>(
            pairIL, histSA, nblkA, halfIL, cpbA, I, ofsIL, tuIL,
            pairBL, histSB, nblkB, halfBL, cpbB, NB, ofsBL, tuBL);
    } else {
        // fallback: atomic hist -> scan -> atomic scatter
        zero_ints<<<(I + NB + 255) / 256, 256, 0, stream>>>(cnt, I + NB);
        hist_at<<<(halfIL + halfBL + 255) / 256, 256, 0, stream>>>(
            il_cols, halfIL, U, cntIL, bl_cols, halfBL, U, cntBL);
        int nb0 = (I + 255) / 256, nb1 = (NB + 255) / 256;
        scan1h<<<nb0 + nb1, 256, 0, stream>>>(cntIL, I, nb0, part0, cntBL, NB, nb1, part1);
        scan3h<<<nb0 + nb1, 256, 0, stream>>>(
            cntIL, I, nb0, part0, ofsIL, curIL, 1,
            cntBL, NB, nb1, part1, ofsBL, curBL, 1);
        scatter2<<<(halfIL + halfBL + 255) / 256, 256, 0, stream>>>(
            il_rows, il_cols, U, halfIL, curIL, tuIL,
            bl_rows, bl_cols, U, halfBL, curBL, tuBL);
    }

    // 6-7. two fused layers (octet structure: 8 rows/wave, XCD-chunked)
    float invuA = 1.f / suA;
    float invuB = 1.f / suB;
    int wavesTot = ((nIL + 7) >> 3) + ((nBL + 7) >> 3);
    int lgrid = (wavesTot * 64 + 255) / 256;
    if (degUI == 30 && degUB == 20) {
        layer8_fused<30, 20, 0><<<lgrid, 256, 0, stream>>>(
            il_cols, il_vals, ofsIL, tuIL, f0A, f1A, nrmA, users_feature, items_feature, accILbf,
            U, nIL, degUI, invuA,
            bl_cols, bl_vals, ofsBL, tuBL, f0B, f1B, nrmB, users_feature, bundles_feature, accBLbf,
            U, nBL, degUB, invuB, 0.5f);
        layer8_fused<30, 20, 1><<<lgrid, 256, 0, stream>>>(
            il_cols, il_vals, ofsIL, tuIL, f1A, f0A, nrmA, users_feature, items_feature, accILbf,
            U, nIL, degUI, invuA,
            bl_cols, bl_vals, ofsBL, tuBL, f1B, f0B, nrmB, users_feature, bundles_feature, accBLbf,
            U, nBL, degUB, invuB, 1.f / 3.f);
    } else {
        layer8_fused<0, 0, 0><<<lgrid, 256, 0, stream>>>(
            il_cols, il_vals, ofsIL, tuIL, f0A, f1A, nrmA, users_feature, items_feature, accILbf,
            U, nIL, degUI, invuA,
            bl_cols, bl_vals, ofsBL, tuBL, f0B, f1B, nrmB, users_feature, bundles_feature, accBLbf,
            U, nBL, degUB, invuB, 0.5f);
        layer8_fused<0, 0, 1><<<lgrid, 256, 0, stream>>>(
            il_cols, il_vals, ofsIL, tuIL, f1A, f0A, nrmA, users_feature, items_feature, accILbf,
            U, nIL, degUI, invuA,
            bl_cols, bl_vals, ofsBL, tuBL, f1B, f0B, nrmB, users_feature, bundles_feature, accBLbf,
            U, nBL, degUB, invuB, 1.f / 3.f);
    }

    // 8. scoring
    if (M == 40) {
        score_kernel_t<40><<<(BATCH * 64 + 255) / 256, 256, 0, stream>>>(
            accILbf, accBLbf, bitem, bmask, users, bundles, fw1, fb1, fw2, fb2,
            (float*)d_out, U, K, BATCH);
    } else {
        score_kernel_gen<<<(BATCH * 64 + 255) / 256, 256, 0, stream>>>(
            accILbf, accBLbf, bitem, bmask, users, bundles, fw1, fb1, fw2, fb2,
            (float*)d_out, U, M, K, BATCH);
    }
}

// Round 15
// 144.274 us; speedup vs baseline: 1.1360x; 1.1360x over previous
//
#include <hip/hip_runtime.h>
#include <hip/hip_bf16.h>
#include <math.h>

// ---------------------------------------------------------------------------
// Bundle recommendation forward (BGCN-style).
// r14 changes vs r13 (REVERT + score prefetch):
//  - layers reverted to r11 body (single-stream, unroll 10, no swizzle):
//    r13's dual-stream traded occupancy (VGPR 92, occ 11.5%) for ILP at net
//    loss; occ x ILP product stayed constant -> latency floor confirmed.
//  - score: K==2 fast path prefetches BOTH bundles' metadata (bitem row,
//    mask row, accBL row) before any compute; two independent inlined
//    score_one evaluations let the compiler interleave gather streams.
// ---------------------------------------------------------------------------

typedef unsigned short ushortT;
#define CHUNK 8192

__device__ __forceinline__ float wSum(float v) {
#pragma unroll
    for (int o = 32; o >= 1; o >>= 1) v += __shfl_xor(v, o, 64);
    return v;
}
__device__ __forceinline__ float wMax(float v) {
#pragma unroll
    for (int o = 32; o >= 1; o >>= 1) v = fmaxf(v, __shfl_xor(v, o, 64));
    return v;
}
__device__ __forceinline__ float bf2f(ushortT u) {
    return __uint_as_float(((unsigned int)u) << 16);
}
__device__ __forceinline__ ushortT f2bf(float f) {  // round-nearest-even
    unsigned int x = __float_as_uint(f);
    return (ushortT)((x + 0x7fffu + ((x >> 16) & 1u)) >> 16);
}
__device__ __forceinline__ void up2(unsigned int u, float& lo, float& hi) {
    lo = __uint_as_float(u << 16);
    hi = __uint_as_float(u & 0xffff0000u);
}
__device__ __forceinline__ unsigned int pk2(float lo, float hi) {
    return ((unsigned int)f2bf(hi) << 16) | f2bf(lo);
}

__global__ void zero_ints(int* __restrict__ p, int n) {
    int i = blockIdx.x * blockDim.x + threadIdx.x;
    if (i < n) p[i] = 0;
}

// fallback: atomic global histogram of item-side degrees
__global__ void hist_at(const int* __restrict__ colsA, int halfA, int nAA, int* __restrict__ cntA,
                        const int* __restrict__ colsB, int halfB, int nAB, int* __restrict__ cntB) {
    int i = blockIdx.x * blockDim.x + threadIdx.x;
    if (i < halfA) atomicAdd(&cntA[colsA[i] - nAA], 1);
    else if (i < halfA + halfB) {
        int j = i - halfA;
        atomicAdd(&cntB[colsB[j] - nAB], 1);
    }
}

// fused: per-chunk LDS coarse histogram (bucket-major out) + bf16 f0 build
__global__ void prep_f(
    const int* __restrict__ colsA, int halfA, int nblkA, int cpbA,
    int* __restrict__ histTA,
    const int* __restrict__ colsB, int halfB, int nblkB, int cpbB,
    int* __restrict__ histTB,
    int nA0,
    const float* __restrict__ uf, const float* __restrict__ itf,
    const float* __restrict__ buf,
    ushortT* __restrict__ f0A, int nTotA,
    ushortT* __restrict__ f0B, int nTotB) {
    __shared__ int h[256];
    int blk = blockIdx.x, t = threadIdx.x;
    int edgeBlks = nblkA + nblkB;
    if (blk < edgeBlks) {
        const int* cols; int half, nblk, cpb, k; int* histT;
        if (blk < nblkA) { cols = colsA; half = halfA; nblk = nblkA; cpb = cpbA; histT = histTA; k = blk; }
        else             { cols = colsB; half = halfB; nblk = nblkB; cpb = cpbB; histT = histTB; k = blk - nblkA; }
        h[t] = 0;
        __syncthreads();
        int s = k * CHUNK, e = min(s + CHUNK, half);
        for (int i = s + t; i < e; i += 256) atomicAdd(&h[(cols[i] - nA0) / cpb], 1);
        __syncthreads();
        histT[t * nblk + k] = h[t];  // bucket-major
    } else {
        int idx = (blk - edgeBlks) * 256 + t;
        int totA = nTotA * 64;
        if (idx < totA) {
            int r = idx >> 6;
            f0A[idx] = f2bf((r < nA0) ? uf[idx] : itf[idx - nA0 * 64]);
        } else if (idx < totA + nTotB * 64) {
            int j = idx - totA;
            int r = j >> 6;
            f0B[j] = f2bf((r < nA0) ? uf[j] : buf[j - nA0 * 64]);
        }
    }
}

// --- 2-array hierarchical scan ---
__global__ void scan1h(const int* c0, int n0, int nb0, int* p0,
                       const int* c1, int n1, int nb1, int* p1) {
    int blk = blockIdx.x, t = threadIdx.x;
    const int* cnt; int n; int* part; int cb;
    if (blk < nb0) { cnt = c0; n = n0; part = p0; cb = blk; }
    else           { cnt = c1; n = n1; part = p1; cb = blk - nb0; }
    int i = cb * 256 + t;
    int v = (i < n) ? cnt[i] : 0;
#pragma unroll
    for (int o = 32; o >= 1; o >>= 1) v += __shfl_xor(v, o, 64);
    __shared__ int sm[4];
    if ((t & 63) == 0) sm[t >> 6] = v;
    __syncthreads();
    if (t == 0) part[cb] = sm[0] + sm[1] + sm[2] + sm[3];
}

// 2-array scan pass 2: per-block base reduction (strided, any cb) + local
// exclusive scan. Optional cur copy + tail write.
__global__ void scan3h(const int* c0, int n0, int nb0, const int* p0, int* o0, int* u0, int t0,
                       const int* c1, int n1, int nb1, const int* p1, int* o1, int* u1, int t1) {
    __shared__ int sm[256];
    int blk = blockIdx.x, t = threadIdx.x;
    const int *cnt, *part; int *ofs, *cur; int n, cb, tail;
    if (blk < nb0) { cnt = c0; n = n0; part = p0; ofs = o0; cur = u0; cb = blk; tail = t0; }
    else           { cnt = c1; n = n1; part = p1; ofs = o1; cur = u1; cb = blk - nb0; tail = t1; }
    int acc = 0;
    for (int j = t; j < cb; j += 256) acc += part[j];
    sm[t] = acc;
    __syncthreads();
    for (int o = 128; o >= 1; o >>= 1) {
        if (t < o) sm[t] += sm[t + o];
        __syncthreads();
    }
    int base = sm[0];
    __syncthreads();
    int i = cb * 256 + t;
    int v = (i < n) ? cnt[i] : 0;
    sm[t] = v;
    __syncthreads();
    for (int o = 1; o < 256; o <<= 1) {
        int x = (t >= o) ? sm[t - o] : 0;
        __syncthreads();
        sm[t] += x;
        __syncthreads();
    }
    int excl = sm[t] - v + base;
    if (i < n) {
        ofs[i] = excl;
        if (cur) cur[i] = excl;
        if (tail && i == n - 1) ofs[n] = excl + v;
    }
}

// pass 1b: scatter packed (col<<16|user) into bucket-contiguous regions
__global__ void p1scat(const int* __restrict__ rowsA, const int* __restrict__ colsA,
                       int halfA, int nblkA, int cpbA, int nAA,
                       const int* __restrict__ hsA, unsigned int* __restrict__ pairA,
                       const int* __restrict__ rowsB, const int* __restrict__ colsB,
                       int halfB, int nblkB, int cpbB, int nAB,
                       const int* __restrict__ hsB, unsigned int* __restrict__ pairB) {
    __shared__ int cur[256];
    int blk = blockIdx.x, t = threadIdx.x;
    const int *rows, *cols, *hs; int half, nblk, cpb, nA0, k; unsigned int* pair;
    if (blk < nblkA) { rows = rowsA; cols = colsA; hs = hsA; pair = pairA;
                       half = halfA; nblk = nblkA; cpb = cpbA; nA0 = nAA; k = blk; }
    else             { rows = rowsB; cols = colsB; hs = hsB; pair = pairB;
                       half = halfB; nblk = nblkB; cpb = cpbB; nA0 = nAB; k = blk - nblkA; }
    cur[t] = hs[t * nblk + k];
    __syncthreads();
    int s = k * CHUNK, e = min(s + CHUNK, half);
    for (int i = s + t; i < e; i += 256) {
        int c = cols[i] - nA0;
        int pos = atomicAdd(&cur[c / cpb], 1);
        pair[pos] = ((unsigned int)c << 16) | (unsigned int)rows[i];
    }
}

// pass 2: one block per coarse bucket. Computes per-column offsets LOCALLY
// (LDS histogram + scan over <=256 columns), writes ofs[] AND exact-CSR tu[].
__global__ void p2scat_ofs(
    const unsigned int* __restrict__ pairA, const int* __restrict__ hsA,
    int nblkA, int halfA, int cpbA, int nColsA,
    int* __restrict__ ofsA, int* __restrict__ tuA,
    const unsigned int* __restrict__ pairB, const int* __restrict__ hsB,
    int nblkB, int halfB, int cpbB, int nColsB,
    int* __restrict__ ofsB, int* __restrict__ tuB) {
    __shared__ int lcnt[256];
    __shared__ int lofs[256];
    int blk = blockIdx.x, t = threadIdx.x;
    const unsigned int* pair; const int* hs; int nblk, half, cpb, nCols, b; int *ofs, *tu;
    if (blk < 256) { pair = pairA; hs = hsA; nblk = nblkA; half = halfA; cpb = cpbA;
                     nCols = nColsA; ofs = ofsA; tu = tuA; b = blk; }
    else           { pair = pairB; hs = hsB; nblk = nblkB; half = halfB; cpb = cpbB;
                     nCols = nColsB; ofs = ofsB; tu = tuB; b = blk - 256; }
    int c0 = b * cpb;
    if (c0 >= nCols) return;
    int c1 = min(c0 + cpb, nCols);
    int w = c1 - c0;
    int s = hs[b * nblk];
    int e = (b == 255) ? half : hs[(b + 1) * nblk];
    lcnt[t] = 0;
    __syncthreads();
    for (int i = s + t; i < e; i += 256)
        atomicAdd(&lcnt[(int)(pair[i] >> 16) - c0], 1);
    __syncthreads();
    int v = lcnt[t];
    lofs[t] = v;
    __syncthreads();
    for (int o = 1; o < 256; o <<= 1) {
        int x = (t >= o) ? lofs[t - o] : 0;
        __syncthreads();
        lofs[t] += x;
        __syncthreads();
    }
    int excl = lofs[t] - v + s;   // global CSR offset of column c0+t
    if (t < w) ofs[c0 + t] = excl;
    if (t == 0 && c1 == nCols) ofs[nCols] = e;
    __syncthreads();
    lofs[t] = excl;               // cursors
    __syncthreads();
    for (int i = s + t; i < e; i += 256) {
        unsigned int pr = pair[i];
        int pos = atomicAdd(&lofs[(int)(pr >> 16) - c0], 1);
        tu[pos] = (int)(pr & 0xffffu);
    }
}

// fallback scatter (generic shapes)
__global__ void scatter2(const int* __restrict__ rowsA, const int* __restrict__ colsA,
                         int nAA, int halfA, int* __restrict__ curA, int* __restrict__ tuA,
                         const int* __restrict__ rowsB, const int* __restrict__ colsB,
                         int nAB, int halfB, int* __restrict__ curB, int* __restrict__ tuB) {
    int i = blockIdx.x * blockDim.x + threadIdx.x;
    if (i < halfA) {
        int c = colsA[i] - nAA;
        int p = atomicAdd(&curA[c], 1);
        tuA[p] = rowsA[i];
    } else if (i < halfA + halfB) {
        int j = i - halfA;
        int c = colsB[j] - nAB;
        int p = atomicAdd(&curB[c], 1);
        tuB[p] = rowsB[j];
    }
}

// octet layer body: octet handles one row; lane p owns dims [8p..8p+7].
// LAST=0: write f1 (bf16) + nrm[row]=inv_nrm.
// LAST=1: accOut = bf16(orig_f32 + f1*nrm1 + f2*inv_nrm2).
template <int DEG, int LAST>
__device__ __forceinline__ void layer8_body(
    const int* __restrict__ cols, const float* __restrict__ vals,
    const int* __restrict__ ofs, const int* __restrict__ tuser,
    const ushortT* __restrict__ f, ushortT* __restrict__ fnext,
    float* __restrict__ nrm,
    const float* __restrict__ origU, const float* __restrict__ origO,
    ushortT* __restrict__ accOut,
    int row, int p, int nA, int nTot, int deg, float invu, float inv_s) {
    if (row >= nTot) return;  // whole octet inactive together
    float a[8] = {0.f, 0.f, 0.f, 0.f, 0.f, 0.f, 0.f, 0.f};
    if (row < nA) {
        const int* cp = cols + (long)row * deg;
        const float* vp = vals + (long)row * deg;
        if constexpr (DEG > 0) {
#pragma unroll 10
            for (int e = 0; e < DEG; ++e) {
                int c = cp[e];
                float vv = vp[e];
                uint4 rv = *(const uint4*)(f + ((long)c << 6) + (p << 3));
                float x0, x1;
                up2(rv.x, x0, x1); a[0] = fmaf(vv, x0, a[0]); a[1] = fmaf(vv, x1, a[1]);
                up2(rv.y, x0, x1); a[2] = fmaf(vv, x0, a[2]); a[3] = fmaf(vv, x1, a[3]);
                up2(rv.z, x0, x1); a[4] = fmaf(vv, x0, a[4]); a[5] = fmaf(vv, x1, a[5]);
                up2(rv.w, x0, x1); a[6] = fmaf(vv, x0, a[6]); a[7] = fmaf(vv, x1, a[7]);
            }
        } else {
#pragma unroll 4
            for (int e = 0; e < deg; ++e) {
                int c = cp[e];
                float vv = vp[e];
                uint4 rv = *(const uint4*)(f + ((long)c << 6) + (p << 3));
                float x0, x1;
                up2(rv.x, x0, x1); a[0] = fmaf(vv, x0, a[0]); a[1] = fmaf(vv, x1, a[1]);
                up2(rv.y, x0, x1); a[2] = fmaf(vv, x0, a[2]); a[3] = fmaf(vv, x1, a[3]);
                up2(rv.z, x0, x1); a[4] = fmaf(vv, x0, a[4]); a[5] = fmaf(vv, x1, a[5]);
                up2(rv.w, x0, x1); a[6] = fmaf(vv, x0, a[6]); a[7] = fmaf(vv, x1, a[7]);
            }
        }
    } else {
        int r2 = row - nA;
        int s = ofs[r2], e2 = ofs[r2 + 1];
#pragma unroll 8
        for (int j = s; j < e2; ++j) {
            int uu = tuser[j];
            uint4 rv = *(const uint4*)(f + ((long)uu << 6) + (p << 3));
            float x0, x1;
            up2(rv.x, x0, x1); a[0] += x0; a[1] += x1;
            up2(rv.y, x0, x1); a[2] += x0; a[3] += x1;
            up2(rv.z, x0, x1); a[4] += x0; a[5] += x1;
            up2(rv.w, x0, x1); a[6] += x0; a[7] += x1;
        }
        float invi = 1.f / (sqrtf((float)(e2 - s)) + 1e-8f);
        float sc = invi * invu;
#pragma unroll
        for (int d = 0; d < 8; ++d) a[d] *= sc;
    }
    float ss = 0.f;
#pragma unroll
    for (int d = 0; d < 8; ++d) {
        a[d] *= inv_s;
        ss = fmaf(a[d], a[d], ss);
    }
    ss += __shfl_xor(ss, 1, 64);
    ss += __shfl_xor(ss, 2, 64);
    ss += __shfl_xor(ss, 4, 64);
    float inv_nrm = 1.f / fmaxf(sqrtf(ss), 1e-12f);
    long base = ((long)row << 6) + (p << 3);
    if constexpr (!LAST) {
        if (p == 0) nrm[row] = inv_nrm;
        uint4 fb;
        fb.x = pk2(a[0], a[1]);
        fb.y = pk2(a[2], a[3]);
        fb.z = pk2(a[4], a[5]);
        fb.w = pk2(a[6], a[7]);
        *(uint4*)(fnext + base) = fb;
    } else {
        const float* op = (row < nA) ? (origU + base)
                                     : (origO + (((long)(row - nA)) << 6) + (p << 3));
        float4 c0 = *(const float4*)op;
        float4 c1 = *(const float4*)(op + 4);
        float n1 = nrm[row];
        uint4 f1v = *(const uint4*)(f + base);   // own row of layer-1 output
        float x0, x1, x2, x3, x4, x5, x6, x7;
        up2(f1v.x, x0, x1);
        up2(f1v.y, x2, x3);
        up2(f1v.z, x4, x5);
        up2(f1v.w, x6, x7);
        uint4 ob;
        ob.x = pk2(c0.x + x0 * n1 + a[0] * inv_nrm, c0.y + x1 * n1 + a[1] * inv_nrm);
        ob.y = pk2(c0.z + x2 * n1 + a[2] * inv_nrm, c0.w + x3 * n1 + a[3] * inv_nrm);
        ob.z = pk2(c1.x + x4 * n1 + a[4] * inv_nrm, c1.y + x5 * n1 + a[5] * inv_nrm);
        ob.w = pk2(c1.z + x6 * n1 + a[6] * inv_nrm, c1.w + x7 * n1 + a[7] * inv_nrm);
        *(uint4*)(accOut + base) = ob;
    }
}

template <int DA, int DB, int LAST>
__global__ void __launch_bounds__(256) layer8_fused(
    const int* colsA, const float* valsA, const int* ofsA, const int* tuA,
    const ushortT* fA, ushortT* fnA, float* nrmA,
    const float* origUA, const float* origOA, ushortT* accOutA,
    int nAA, int nTotA, int degA, float invuA,
    const int* colsB, const float* valsB, const int* ofsB, const int* tuB,
    const ushortT* fB, ushortT* fnB, float* nrmB,
    const float* origUB, const float* origOB, ushortT* accOutB,
    int nAB, int nTotB, int degB, float invuB,
    float inv_s) {
    int gw = (blockIdx.x * blockDim.x + threadIdx.x) >> 6;
    int lane = threadIdx.x & 63;
    int oct = lane >> 3, p = lane & 7;
    int wA = (nTotA + 7) >> 3;
    int wB = (nTotB + 7) >> 3;
    if (gw < wA) {
        layer8_body<DA, LAST>(colsA, valsA, ofsA, tuA, fA, fnA, nrmA, origUA, origOA, accOutA,
                              gw * 8 + oct, p, nAA, nTotA, degA, invuA, inv_s);
    } else if (gw < wA + wB) {
        layer8_body<DB, LAST>(colsB, valsB, ofsB, tuB, fB, fnB, nrmB, origUB, origOB, accOutB,
                              (gw - wA) * 8 + oct, p, nAB, nTotB, degB, invuB, inv_s);
    }
}

// per-bundle score body: given prefetched metadata, compute fused score
template <int MM>
__device__ __forceinline__ float score_one(
    const ushortT* __restrict__ accIL, int U, const float* q8, int pos, int lane,
    int idl, unsigned long long vmask, float blu, float blb, float g) {
    float el = -1e30f, lr = 0.f;  // lane m ends up holding logit m
#pragma unroll
    for (int i = 0; i < MM / 8; ++i) {
        // octet (lane>>3) computes item 8*i + (lane>>3)
        int id = __shfl(idl, 8 * i + (lane >> 3), 64);
        uint4 rv = *(const uint4*)(accIL + (((long)(U + id)) << 6) + (pos << 3));
        float a0, a1, s;
        up2(rv.x, a0, a1);
        s = fmaf(q8[0], a0, q8[1] * a1);
        up2(rv.y, a0, a1);
        s = fmaf(q8[2], a0, fmaf(q8[3], a1, s));
        up2(rv.z, a0, a1);
        s = fmaf(q8[4], a0, fmaf(q8[5], a1, s));
        up2(rv.w, a0, a1);
        s = fmaf(q8[6], a0, fmaf(q8[7], a1, s));
        // butterfly within the 8-lane group: all 8 lanes get the dot
        s += __shfl_xor(s, 1, 64);
        s += __shfl_xor(s, 2, 64);
        s += __shfl_xor(s, 4, 64);
        // assemble to lane m = 8*i + oct: read from octet (lane&7)
        float v = __shfl(s, (lane & 7) << 3, 64);
        if ((lane >> 3) == i) {
            lr = v;
            el = ((vmask >> lane) & 1ull) ? v : -1e9f;
        }
    }
    float bl = wSum(blu * blb);
    float maxl = wMax(el);
    float pe = __expf(el - maxl);   // lanes >= MM: exp(-inf) -> 0
    float sum = wSum(pe);
    float il = wSum(pe * lr) / sum;
    return g * il + (1.f - g) * bl;
}

// one wave per batch row; K bundles per wave. MM = compile-time bundle size
// (must be divisible by 8).
template <int MM>
__global__ void __launch_bounds__(256) score_kernel_t(
    const ushortT* __restrict__ accIL, const ushortT* __restrict__ accBL,
    const int* __restrict__ bitem, const unsigned char* __restrict__ mask8,
    const int* __restrict__ users, const int* __restrict__ bundles,
    const float* __restrict__ fw1, const float* __restrict__ fb1,
    const float* __restrict__ fw2, const float* __restrict__ fb2,
    float* __restrict__ out, int U, int K, int B) {
    int b = (blockIdx.x * blockDim.x + threadIdx.x) >> 6;
    int lane = threadIdx.x & 63;
    if (b >= B) return;
    // mask layout self-detection (lengths >= 10 so element 1 is True):
    // u8-bool -> byte 1 == 1 ; int32 -> byte 1 == 0 (high byte of value 1)
    bool mu8 = (mask8[1] != 0);
    const int* m32 = (const int*)mask8;

    int u = users[b];
    const ushortT* qrow = accIL + ((long)u << 6);
    float q = bf2f(qrow[lane]);
    float blu = bf2f(accBL[((long)u << 6) + lane]);

    // q fragment for 8-lane dots: this lane's 8 dims [8*pos .. 8*pos+7]
    int pos = lane & 7;
    uint4 qv = *(const uint4*)(qrow + (pos << 3));
    float q8[8];
    up2(qv.x, q8[0], q8[1]);
    up2(qv.y, q8[2], q8[3]);
    up2(qv.z, q8[4], q8[5]);
    up2(qv.w, q8[6], q8[7]);

    // gate MLP (user-dependent only), 4 independent accumulator chains
    float h0 = fb1[lane], h1 = 0.f, h2 = 0.f, h3 = 0.f;
#pragma unroll
    for (int i = 0; i < 64; i += 4) {
        h0 = fmaf(__shfl(q, i, 64),     fw1[i * 64 + lane],       h0);
        h1 = fmaf(__shfl(q, i + 1, 64), fw1[(i + 1) * 64 + lane], h1);
        h2 = fmaf(__shfl(q, i + 2, 64), fw1[(i + 2) * 64 + lane], h2);
        h3 = fmaf(__shfl(q, i + 3, 64), fw1[(i + 3) * 64 + lane], h3);
    }
#pragma unroll
    for (int i = 0; i < 64; i += 4) {
        h0 = fmaf(__shfl(blu, i, 64),     fw1[(64 + i) * 64 + lane],     h0);
        h1 = fmaf(__shfl(blu, i + 1, 64), fw1[(64 + i + 1) * 64 + lane], h1);
        h2 = fmaf(__shfl(blu, i + 2, 64), fw1[(64 + i + 2) * 64 + lane], h2);
        h3 = fmaf(__shfl(blu, i + 3, 64), fw1[(64 + i + 3) * 64 + lane], h3);
    }
    float h = fmaxf((h0 + h1) + (h2 + h3), 0.f);
    float gd = wSum(h * fw2[lane]) + fb2[0];
    float g = 1.f / (1.f + __expf(-gd));

    if (K == 2) {
        // prefetch BOTH bundles' metadata before any compute
        int bd0 = bundles[b * 2];
        int bd1 = bundles[b * 2 + 1];
        long ib0 = (long)bd0 * MM;
        long ib1 = (long)bd1 * MM;
        int idl0 = (lane < MM) ? bitem[ib0 + lane] : 0;
        int idl1 = (lane < MM) ? bitem[ib1 + lane] : 0;
        float blb0 = bf2f(accBL[((long)(U + bd0)) * 64 + lane]);
        float blb1 = bf2f(accBL[((long)(U + bd1)) * 64 + lane]);
        bool mv0 = (lane < MM) ? (mu8 ? (mask8[ib0 + lane] != 0) : (m32[ib0 + lane] != 0)) : false;
        bool mv1 = (lane < MM) ? (mu8 ? (mask8[ib1 + lane] != 0) : (m32[ib1 + lane] != 0)) : false;
        unsigned long long vm0 = __ballot(mv0);
        unsigned long long vm1 = __ballot(mv1);
        float s0 = score_one<MM>(accIL, U, q8, pos, lane, idl0, vm0, blu, blb0, g);
        float s1 = score_one<MM>(accIL, U, q8, pos, lane, idl1, vm1, blu, blb1, g);
        if (lane == 0) {
            out[b * 2] = s0;
            out[b * 2 + 1] = s1;
        }
    } else {
        for (int k = 0; k < K; ++k) {
            int bd = bundles[b * K + k];
            float blb = bf2f(accBL[((long)(U + bd)) * 64 + lane]);
            long ib = (long)bd * MM;
            int idl = (lane < MM) ? bitem[ib + lane] : 0;
            bool mv = (lane < MM) ? (mu8 ? (mask8[ib + lane] != 0) : (m32[ib + lane] != 0))
                                  : false;
            unsigned long long vmask = __ballot(mv);
            float sc = score_one<MM>(accIL, U, q8, pos, lane, idl, vmask, blu, blb, g);
            if (lane == 0) out[b * K + k] = sc;
        }
    }
}

// generic-M fallback (runtime M)
__global__ void __launch_bounds__(256) score_kernel_gen(
    const ushortT* __restrict__ accIL, const ushortT* __restrict__ accBL,
    const int* __restrict__ bitem, const unsigned char* __restrict__ mask8,
    const int* __restrict__ users, const int* __restrict__ bundles,
    const float* __restrict__ fw1, const float* __restrict__ fb1,
    const float* __restrict__ fw2, const float* __restrict__ fb2,
    float* __restrict__ out, int U, int M, int K, int B) {
    int b = (blockIdx.x * blockDim.x + threadIdx.x) >> 6;
    int lane = threadIdx.x & 63;
    if (b >= B) return;
    bool mu8 = (mask8[1] != 0);
    const int* m32 = (const int*)mask8;
    int u = users[b];
    float q = bf2f(accIL[((long)u << 6) + lane]);
    float blu = bf2f(accBL[((long)u << 6) + lane]);
    float h = fb1[lane];
#pragma unroll 8
    for (int i = 0; i < 64; ++i) h = fmaf(__shfl(q, i, 64), fw1[i * 64 + lane], h);
#pragma unroll 8
    for (int i = 0; i < 64; ++i) h = fmaf(__shfl(blu, i, 64), fw1[(64 + i) * 64 + lane], h);
    h = fmaxf(h, 0.f);
    float gd = wSum(h * fw2[lane]) + fb2[0];
    float g = 1.f / (1.f + __expf(-gd));
    for (int k = 0; k < K; ++k) {
        int bd = bundles[b * K + k];
        float blb = bf2f(accBL[((long)(U + bd)) * 64 + lane]);
        float bl = wSum(blu * blb);
        long ib = (long)bd * M;
        int idl = (lane < M) ? bitem[ib + lane] : 0;
        bool mv = (lane < M) ? (mu8 ? (mask8[ib + lane] != 0) : (m32[ib + lane] != 0))
                             : false;
        unsigned long long vmask = __ballot(mv);
        float el = -1e30f, lr = 0.f;
#pragma unroll 8
        for (int m = 0; m < M; ++m) {
            int id = __shfl(idl, m, 64);
            float it = bf2f(accIL[((long)(U + id)) * 64 + lane]);
            float l = wSum(q * it);
            float lm = ((vmask >> m) & 1ull) ? l : -1e9f;
            if (lane == m) { el = lm; lr = l; }
        }
        float maxl = wMax(el);
        float pe = __expf(el - maxl);
        float sum = wSum(pe);
        float il = wSum(pe * lr) / sum;
        if (lane == 0) out[b * K + k] = g * il + (1.f - g) * bl;
    }
}

extern "C" void kernel_launch(void* const* d_in, const int* in_sizes, int n_in,
                              void* d_out, int out_size, void* d_ws, size_t ws_size,
                              hipStream_t stream) {
    const float* users_feature   = (const float*)d_in[0];
    const float* items_feature   = (const float*)d_in[1];
    const float* bundles_feature = (const float*)d_in[2];
    const float* fw1 = (const float*)d_in[3];
    const float* fb1 = (const float*)d_in[4];
    const float* fw2 = (const float*)d_in[5];
    const float* fb2 = (const float*)d_in[6];
    const int*   il_rows = (const int*)d_in[7];
    const int*   il_cols = (const int*)d_in[8];
    const float* il_vals = (const float*)d_in[9];
    const int*   bl_rows = (const int*)d_in[10];
    const int*   bl_cols = (const int*)d_in[11];
    const float* bl_vals = (const float*)d_in[12];
    const int*   bitem   = (const int*)d_in[13];
    const unsigned char* bmask = (const unsigned char*)d_in[14];
    const int*   users   = (const int*)d_in[15];
    const int*   bundles = (const int*)d_in[16];

    const int D = 64;
    int U  = in_sizes[0] / D;
    int I  = in_sizes[1] / D;
    int NB = in_sizes[2] / D;
    int nnzIL = in_sizes[7];
    int nnzBL = in_sizes[10];
    int degUI = (nnzIL / 2) / U;
    int degUB = (nnzBL / 2) / U;
    int M = in_sizes[13] / NB;
    int BATCH = in_sizes[15];
    int K = in_sizes[16] / BATCH;
    int nIL = U + I;
    int nBL = U + NB;
    int halfIL = U * degUI;
    int halfBL = U * degUB;

    char* wsB = (char*)d_ws;
    size_t off = 0;
    auto alc = [&](size_t bytes) -> void* {
        void* p = wsB + off;
        off = (off + bytes + 255) & ~(size_t)255;
        return p;
    };
    ushortT* accILbf = (ushortT*)alc((size_t)nIL * 64 * 2);
    ushortT* accBLbf = (ushortT*)alc((size_t)nBL * 64 * 2);
    ushortT* f0A = (ushortT*)alc((size_t)nIL * 64 * 2);
    ushortT* f1A = (ushortT*)alc((size_t)nIL * 64 * 2);
    ushortT* f0B = (ushortT*)alc((size_t)nBL * 64 * 2);
    ushortT* f1B = (ushortT*)alc((size_t)nBL * 64 * 2);
    float* nrmA = (float*)alc((size_t)nIL * 4);
    float* nrmB = (float*)alc((size_t)nBL * 4);
    int* ofsIL = (int*)alc((size_t)(I + 1) * 4);
    int* tuIL  = (int*)alc((size_t)halfIL * 4);
    int* ofsBL = (int*)alc((size_t)(NB + 1) * 4);
    int* tuBL  = (int*)alc((size_t)halfBL * 4);
    int* cnt   = (int*)alc((size_t)(I + NB) * 4);   // fallback only
    int* cur   = (int*)alc((size_t)(I + NB) * 4);   // fallback only
    int* cntIL = cnt,  *cntBL = cnt + I;
    int* curIL = cur,  *curBL = cur + I;

    // sort-path scratch
    int nblkA = (halfIL + CHUNK - 1) / CHUNK;
    int nblkB = (halfBL + CHUNK - 1) / CHUNK;
    int cpbA = (I + 255) / 256;
    int cpbB = (NB + 255) / 256;
    int LA = 256 * nblkA, LB = 256 * nblkB;
    unsigned int* pairIL = (unsigned int*)alc((size_t)halfIL * 4);
    unsigned int* pairBL = (unsigned int*)alc((size_t)halfBL * 4);
    int* histTA = (int*)alc((size_t)LA * 4);
    int* histSA = (int*)alc((size_t)(LA + 1) * 4);
    int* histTB = (int*)alc((size_t)LB * 4);
    int* histSB = (int*)alc((size_t)(LB + 1) * 4);
    int* part0  = (int*)alc(256 * 4);
    int* part1  = (int*)alc(256 * 4);

    float suA = sqrtf((float)degUI) + 1e-8f;
    float suB = sqrtf((float)degUB) + 1e-8f;

    // 1. edge pass (coarse histogram) || bf16 f0 build
    int elemsTot = (nIL + nBL) * 64;
    int initBlks = (elemsTot + 255) / 256;
    prep_f<<<nblkA + nblkB + initBlks, 256, 0, stream>>>(
        il_cols, halfIL, nblkA, cpbA, histTA,
        bl_cols, halfBL, nblkB, cpbB, histTB,
        U, users_feature, items_feature, bundles_feature,
        f0A, nIL, f0B, nBL);

    bool fast = (I < 65536) && (NB < 65536) && (U < 65536) &&
                (cpbA <= 256) && (cpbB <= 256) &&
                (nblkA >= 1) && (nblkB >= 1) && (nblkA <= 256) && (nblkB <= 256);
    if (fast) {
        // 2-3. scan of bucket-major hist matrices -> per-(bucket,chunk) bases
        scan1h<<<nblkA + nblkB, 256, 0, stream>>>(histTA, LA, nblkA, part0,
                                                  histTB, LB, nblkB, part1);
        scan3h<<<nblkA + nblkB, 256, 0, stream>>>(
            histTA, LA, nblkA, part0, histSA, nullptr, 0,
            histTB, LB, nblkB, part1, histSB, nullptr, 0);
        // 4. bucket-binning scatter (packed col<<16|user)
        p1scat<<<nblkA + nblkB, 256, 0, stream>>>(
            il_rows, il_cols, halfIL, nblkA, cpbA, U, histSA, pairIL,
            bl_rows, bl_cols, halfBL, nblkB, cpbB, U, histSB, pairBL);
        // 5. per-bucket exact CSR build: local column offsets + tu scatter
        p2scat_ofs<<<512, 256, 0, stream>>>(
            pairIL, histSA, nblkA, halfIL, cpbA, I, ofsIL, tuIL,
            pairBL, histSB, nblkB, halfBL, cpbB, NB, ofsBL, tuBL);
    } else {
        // fallback: atomic hist -> scan -> atomic scatter
        zero_ints<<<(I + NB + 255) / 256, 256, 0, stream>>>(cnt, I + NB);
        hist_at<<<(halfIL + halfBL + 255) / 256, 256, 0, stream>>>(
            il_cols, halfIL, U, cntIL, bl_cols, halfBL, U, cntBL);
        int nb0 = (I + 255) / 256, nb1 = (NB + 255) / 256;
        scan1h<<<nb0 + nb1, 256, 0, stream>>>(cntIL, I, nb0, part0, cntBL, NB, nb1, part1);
        scan3h<<<nb0 + nb1, 256, 0, stream>>>(
            cntIL, I, nb0, part0, ofsIL, curIL, 1,
            cntBL, NB, nb1, part1, ofsBL, curBL, 1);
        scatter2<<<(halfIL + halfBL + 255) / 256, 256, 0, stream>>>(
            il_rows, il_cols, U, halfIL, curIL, tuIL,
            bl_rows, bl_cols, U, halfBL, curBL, tuBL);
    }

    // 6-7. two fused layers (octet structure: 8 rows/wave)
    float invuA = 1.f / suA;
    float invuB = 1.f / suB;
    int wavesTot = ((nIL + 7) >> 3) + ((nBL + 7) >> 3);
    int lgrid = (wavesTot * 64 + 255) / 256;
    if (degUI == 30 && degUB == 20) {
        layer8_fused<30, 20, 0><<<lgrid, 256, 0, stream>>>(
            il_cols, il_vals, ofsIL, tuIL, f0A, f1A, nrmA, users_feature, items_feature, accILbf,
            U, nIL, degUI, invuA,
            bl_cols, bl_vals, ofsBL, tuBL, f0B, f1B, nrmB, users_feature, bundles_feature, accBLbf,
            U, nBL, degUB, invuB, 0.5f);
        layer8_fused<30, 20, 1><<<lgrid, 256, 0, stream>>>(
            il_cols, il_vals, ofsIL, tuIL, f1A, f0A, nrmA, users_feature, items_feature, accILbf,
            U, nIL, degUI, invuA,
            bl_cols, bl_vals, ofsBL, tuBL, f1B, f0B, nrmB, users_feature, bundles_feature, accBLbf,
            U, nBL, degUB, invuB, 1.f / 3.f);
    } else {
        layer8_fused<0, 0, 0><<<lgrid, 256, 0, stream>>>(
            il_cols, il_vals, ofsIL, tuIL, f0A, f1A, nrmA, users_feature, items_feature, accILbf,
            U, nIL, degUI, invuA,
            bl_cols, bl_vals, ofsBL, tuBL, f0B, f1B, nrmB, users_feature, bundles_feature, accBLbf,
            U, nBL, degUB, invuB, 0.5f);
        layer8_fused<0, 0, 1><<<lgrid, 256, 0, stream>>>(
            il_cols, il_vals, ofsIL, tuIL, f1A, f0A, nrmA, users_feature, items_feature, accILbf,
            U, nIL, degUI, invuA,
            bl_cols, bl_vals, ofsBL, tuBL, f1B, f0B, nrmB, users_feature, bundles_feature, accBLbf,
            U, nBL, degUB, invuB, 1.f / 3.f);
    }

    // 8. scoring
    if (M == 40) {
        score_kernel_t<40><<<(BATCH * 64 + 255) / 256, 256, 0, stream>>>(
            accILbf, accBLbf, bitem, bmask, users, bundles, fw1, fb1, fw2, fb2,
            (float*)d_out, U, K, BATCH);
    } else {
        score_kernel_gen<<<(BATCH * 64 + 255) / 256, 256, 0, stream>>>(
            accILbf, accBLbf, bitem, bmask, users, bundles, fw1, fb1, fw2, fb2,
            (float*)d_out, U, M, K, BATCH);
    }
}